// Round 27
// baseline (270.576 us; speedup 1.0000x reference)
//
#include <hip/hip_runtime.h>
#include <cstdint>

// ---------- sizes ----------
#define BT_ROWS 4096      // B*T
#define DM      1024
#define DFF     2730
#define DFFP    2816      // padded to /128
#define TSEQ    2048

typedef float  f32x4  __attribute__((ext_vector_type(4)));
typedef __bf16 bf16x8 __attribute__((ext_vector_type(8)));

typedef __attribute__((address_space(1))) const unsigned int as1_uint;
typedef __attribute__((address_space(3))) unsigned int       as3_uint;

__device__ __forceinline__ unsigned short f2bf(float f) {
  union { float f; unsigned int u; } v; v.f = f;
  unsigned int u = v.u;
  return (unsigned short)((u + 0x7fffu + ((u >> 16) & 1u)) >> 16);  // RNE
}
__device__ __forceinline__ float bf2f(unsigned int b) {
  union { unsigned int u; float f; } v; v.u = b << 16;
  return v.f;
}

__device__ __forceinline__ void async_cp16(const void* g, void* l) {
  // 16B-wide global->LDS DMA; LDS dest is wave-uniform base + lane*16
  __builtin_amdgcn_global_load_lds((as1_uint*)(uintptr_t)g, (as3_uint*)(uintptr_t)l, 16, 0, 0);
}

// ---------- fused prep (vectorized) + rmsnorm1 (appended blocks) ----------
#define PREP_BLOCKS 12672
__global__ void prep_kernel(const float* __restrict__ WQ, const float* __restrict__ WK,
                            const float* __restrict__ WV, const float* __restrict__ WOp,
                            const float* __restrict__ W1, const float* __restrict__ W3,
                            const float* __restrict__ W2, const int* __restrict__ pos,
                            unsigned short* __restrict__ Wqkv, unsigned short* __restrict__ Wo,
                            unsigned short* __restrict__ W13i, unsigned short* __restrict__ W2p,
                            float2* __restrict__ cs,
                            const float* __restrict__ x, const float* __restrict__ g1,
                            unsigned short* __restrict__ hbuf) {
  if (blockIdx.x >= PREP_BLOCKS) {           // rmsnorm1: one block per row
    const int row = blockIdx.x - PREP_BLOCKS, tid = threadIdx.x;
    const float4 xv = reinterpret_cast<const float4*>(x + (long)row * DM)[tid];
    float ss = xv.x * xv.x + xv.y * xv.y + xv.z * xv.z + xv.w * xv.w;
#pragma unroll
    for (int o = 32; o > 0; o >>= 1) ss += __shfl_xor(ss, o);
    __shared__ float wsum[4];
    if ((tid & 63) == 0) wsum[tid >> 6] = ss;
    __syncthreads();
    const float inv = rsqrtf((wsum[0] + wsum[1] + wsum[2] + wsum[3]) * (1.f / DM) + 1e-5f);
    const float4 gv = reinterpret_cast<const float4*>(g1)[tid];
    ushort4 o4;
    o4.x = f2bf(xv.x * inv * gv.x);
    o4.y = f2bf(xv.y * inv * gv.y);
    o4.z = f2bf(xv.z * inv * gv.z);
    o4.w = f2bf(xv.w * inv * gv.w);
    reinterpret_cast<ushort4*>(hbuf + (long)row * DM)[tid] = o4;
    return;
  }
  long grp = (long)blockIdx.x * 256 + threadIdx.x;
  if (grp < 1048576) {                       // 4 square 1024x1024 mats, float4
    const int j = (int)(grp >> 18);
    const long t = (grp & 262143L) * 4;
    const float* s = (j == 0) ? WQ : (j == 1) ? WK : (j == 2) ? WV : WOp;
    unsigned short* d = (j < 3) ? (Wqkv + (size_t)j * 1048576) : Wo;
    const float4 v = *reinterpret_cast<const float4*>(s + t);
    *reinterpret_cast<ushort4*>(d + t) =
        make_ushort4(f2bf(v.x), f2bf(v.y), f2bf(v.z), f2bf(v.w));
    return;
  }
  grp -= 1048576;
  if (grp < 1441792) {                       // W1/W3 row-interleaved + pad
    const int half = (int)(grp / 720896);
    const long t = (grp % 720896) * 4;
    const int r = (int)(t >> 10), c = (int)(t & 1023);
    ushort4 o = make_ushort4(0, 0, 0, 0);
    if (r < DFF) {
      const float4 v = *reinterpret_cast<const float4*>(((half ? W3 : W1) + (long)r * 1024 + c));
      o = make_ushort4(f2bf(v.x), f2bf(v.y), f2bf(v.z), f2bf(v.w));
    }
    *reinterpret_cast<ushort4*>(W13i + ((long)2 * r + half) * 1024 + c) = o;
    return;
  }
  grp -= 1441792;
  if (grp < 720896) {                        // W2 col-padded (rows of 2816, /4)
    const long t = grp * 4;
    const int r = (int)(t / DFFP), c = (int)(t % DFFP);
    const float* src = W2 + (long)r * DFF + c;
    ushort4 o;
    o.x = (c     < DFF) ? f2bf(src[0]) : 0;
    o.y = (c + 1 < DFF) ? f2bf(src[1]) : 0;
    o.z = (c + 2 < DFF) ? f2bf(src[2]) : 0;
    o.w = (c + 3 < DFF) ? f2bf(src[3]) : 0;
    *reinterpret_cast<ushort4*>(W2p + t) = o;
    return;
  }
  grp -= 720896;
  if (grp < 32768) {                         // RoPE cos/sin table, 4 entries
    const long i0 = grp * 4;
    const int r = (int)(i0 >> 5);
    const float p = (float)pos[r];
#pragma unroll
    for (int j = 0; j < 4; ++j) {
      const int i = (int)((i0 + j) & 31);
      const float f = powf(10000.f, -(float)(2 * i) * (1.f / 64.f));
      float sv, cv;
      sincosf(p * f, &sv, &cv);
      cs[i0 + j] = make_float2(cv, sv);
    }
  }
}

// ---------- RMSNorm (bf16 in -> bf16 out), one block per row ----------
__global__ void rmsnorm_bf16_kernel(const unsigned short* __restrict__ x, const float* __restrict__ g,
                                    unsigned short* __restrict__ out) {
  const int row = blockIdx.x, tid = threadIdx.x;
  const ushort4 xu = reinterpret_cast<const ushort4*>(x + (long)row * DM)[tid];
  const float x0 = bf2f(xu.x), x1 = bf2f(xu.y), x2 = bf2f(xu.z), x3 = bf2f(xu.w);
  float ss = x0 * x0 + x1 * x1 + x2 * x2 + x3 * x3;
#pragma unroll
  for (int o = 32; o > 0; o >>= 1) ss += __shfl_xor(ss, o);
  __shared__ float wsum[4];
  if ((tid & 63) == 0) wsum[tid >> 6] = ss;
  __syncthreads();
  const float inv = rsqrtf((wsum[0] + wsum[1] + wsum[2] + wsum[3]) * (1.f / DM) + 1e-5f);
  const float4 gv = reinterpret_cast<const float4*>(g)[tid];
  ushort4 o4;
  o4.x = f2bf(x0 * inv * gv.x);
  o4.y = f2bf(x1 * inv * gv.y);
  o4.z = f2bf(x2 * inv * gv.z);
  o4.w = f2bf(x3 * inv * gv.w);
  reinterpret_cast<ushort4*>(out + (long)row * DM)[tid] = o4;
}

// ---------- GEMM: C[M,N] = A[M,K] * B[N,K]^T  (bf16 in, fp32 acc) ----------
// 128xBN tile, BK=64, XOR-swizzled LDS (pre-swizzled global src).
// DB=1: 2-phase dbuf via __syncthreads; DB=0: single-buffer.
// T1 XCD swizzle, y-fastest decode.
template <int EPI, int BN, int DB>
__global__ __launch_bounds__(256) void gemm_bt(
    const unsigned short* __restrict__ A, const unsigned short* __restrict__ B,
    void* __restrict__ C, const float* __restrict__ resid,
    const float2* __restrict__ CS,
    int M, int N, int K, int ldc) {
  constexpr int WNF = BN / 32;              // B-frags per wave (4 or 2)
  __shared__ unsigned short As[(DB + 1) * 128 * 64];
  __shared__ unsigned short Bs[(DB + 1) * BN * 64];
  const int tid = threadIdx.x;
  const int wid = tid >> 6;
  const int lane = tid & 63;
  const int nwg = gridDim.x * gridDim.y;
  int flat = blockIdx.y * gridDim.x + blockIdx.x;
  flat = (flat & 7) * (nwg >> 3) + (flat >> 3);
  const int bx = flat / gridDim.y;
  const int by = flat % gridDim.y;
  const long rowBase = (long)by * 128;
  const long colBase = (long)bx * BN;
  const int wm = (wid >> 1) * 64;
  const int wn = (wid & 1) * (BN / 2);
  const int srow = wid * 8 + (lane >> 3);   // staging row within 32-row group
  const int sc   = lane & 7;                // staging 16B chunk
  const int cs   = (sc ^ (srow & 7)) * 8;   // pre-swizzled source chunk (elems)
  const int fr = lane & 15;                 // fragment row
  const int fg = lane >> 4;                 // fragment k-group

  const f32x4 z4 = {0.f, 0.f, 0.f, 0.f};
  f32x4 acc[4][WNF];
#pragma unroll
  for (int m = 0; m < 4; ++m)
#pragma unroll
    for (int n = 0; n < WNF; ++n) acc[m][n] = z4;

  auto stage = [&](int buf, int kt) {
    const long kOff = (long)kt * 64 + cs;
    char* AsB = (char*)As + buf * 16384;
    char* BsB = (char*)Bs + buf * (BN * 128);
#pragma unroll
    for (int i = 0; i < 4; ++i)
      async_cp16(A + (rowBase + i * 32 + srow) * K + kOff, AsB + i * 4096 + wid * 1024);
#pragma unroll
    for (int i = 0; i < WNF; ++i)
      async_cp16(B + (colBase + i * 32 + srow) * K + kOff, BsB + i * 4096 + wid * 1024);
  };

  auto compute = [&](int buf) {
    const char* AsB = (const char*)As + buf * 16384;
    const char* BsB = (const char*)Bs + buf * (BN * 128);
#pragma unroll
    for (int kk = 0; kk < 2; ++kk) {
      bf16x8 af[4], bfr[WNF];
#pragma unroll
      for (int m = 0; m < 4; ++m)
        af[m] = *(const bf16x8*)(AsB + (wm + m * 16 + fr) * 128 + (((kk * 4 + fg) ^ (fr & 7)) * 16));
#pragma unroll
      for (int n = 0; n < WNF; ++n)
        bfr[n] = *(const bf16x8*)(BsB + (wn + n * 16 + fr) * 128 + (((kk * 4 + fg) ^ (fr & 7)) * 16));
#pragma unroll
      for (int m = 0; m < 4; ++m)
#pragma unroll
        for (int n = 0; n < WNF; ++n)
          acc[m][n] = __builtin_amdgcn_mfma_f32_16x16x32_bf16(af[m], bfr[n], acc[m][n], 0, 0, 0);
    }
  };

  const int nkt = K >> 6;
  if (DB) {
    stage(0, 0);
    __syncthreads();                        // drain vmcnt(0): buf0 ready
    for (int kt = 0; kt < nkt; ++kt) {
      if (kt + 1 < nkt) stage((kt + 1) & 1, kt + 1);   // issue-early (in flight)
      compute(kt & 1);
      __syncthreads();                      // drain-late: next buf ready
    }
  } else {
    for (int kt = 0; kt < nkt; ++kt) {
      if (kt) __syncthreads();              // prev compute done before overwrite
      stage(0, kt);
      __syncthreads();                      // vmcnt(0) drained -> LDS ready
      compute(0);
    }
  }

  const int erow = fg * 4;  // C: col = lane&15, row = (lane>>4)*4 + reg
  if (EPI == 0) {
    unsigned short* Cp = (unsigned short*)C;
#pragma unroll
    for (int m = 0; m < 4; ++m) {
      const long r0 = rowBase + wm + m * 16 + erow;
#pragma unroll
      for (int n = 0; n < WNF; ++n) {
        const long col = colBase + wn + n * 16 + fr;
#pragma unroll
        for (int r = 0; r < 4; ++r) Cp[(r0 + r) * ldc + col] = f2bf(acc[m][n][r]);
      }
    }
  } else if (EPI == 5) {
    unsigned short* Cp = (unsigned short*)C;
#pragma unroll
    for (int m = 0; m < 4; ++m) {
      const long r0 = rowBase + wm + m * 16 + erow;
#pragma unroll
      for (int n = 0; n < WNF; ++n) {
        const long col = colBase + wn + n * 16 + fr;
#pragma unroll
        for (int r = 0; r < 4; ++r) {
          const long o = (r0 + r) * ldc + col;
          Cp[o] = f2bf(acc[m][n][r] + resid[o]);
        }
      }
    }
  } else if (EPI == 6) {
    float* Cf = (float*)C;
    const unsigned short* Rb = (const unsigned short*)(const void*)resid;
#pragma unroll
    for (int m = 0; m < 4; ++m) {
      const long r0 = rowBase + wm + m * 16 + erow;
#pragma unroll
      for (int n = 0; n < WNF; ++n) {
        const long col = colBase + wn + n * 16 + fr;
#pragma unroll
        for (int r = 0; r < 4; ++r) {
          const long o = (r0 + r) * ldc + col;
          Cf[o] = acc[m][n][r] + bf2f(Rb[o]);
        }
      }
    }
  } else {
    // fused RoPE: pair (2i,2i+1) cols via lane^1
    unsigned short* Cp = (unsigned short*)C;
    const int even = !(fr & 1);
#pragma unroll
    for (int m = 0; m < 4; ++m) {
      const long r0 = rowBase + wm + m * 16 + erow;
#pragma unroll
      for (int n = 0; n < WNF; ++n) {
        const long col = colBase + wn + n * 16 + fr;
        const int i = (int)((col & 63) >> 1);
#pragma unroll
        for (int r = 0; r < 4; ++r) {
          const float own = acc[m][n][r];
          const float oth = __shfl_xor(own, 1);
          const float2 cv = CS[(r0 + r) * 32 + i];
          const float v = even ? (cv.x * own - cv.y * oth) : (cv.y * oth + cv.x * own);
          Cp[(r0 + r) * ldc + col] = f2bf(v);
        }
      }
    }
  }
}

// ---------- 256x256 8-PHASE GEMM with fused SwiGLU (W13 only) ----------
// T3+T4+T5: per-phase {ds_read quadrant || stage 1 half-tile -> s_barrier ->
// MFMA(setprio) -> s_barrier}; counted vmcnt(4) only at step boundary.
// Interleaved frag maps (A row = mh*128+m*32+wr*16+fr; B row = nh*128+n*64+
// wc*16+fr) make every wave touch the SAME LDS half per phase, so halves die
// on a provable schedule: A0 after ph2, B0 after ph3, A1/B1 after ph4.
// Stage stream: ph1=(t+1).A1, ph2=(t+1).B1, ph3=(t+2).A0, ph4=(t+2).B0.
#define PH256(BUF, MH, NH, DOSTAGE, SBUF, SKT, SMAT, SHALF)                     \
  {                                                                             \
    const char* Ab = (const char*)Al[BUF];                                      \
    const char* Bb = (const char*)Bl[BUF];                                      \
    bf16x8 af[4][2], bfv[2][2];                                                 \
    _Pragma("unroll")                                                           \
    for (int m = 0; m < 4; ++m) {                                               \
      const int arow = (MH) * 128 + m * 32 + wr * 16 + fr;                      \
      _Pragma("unroll")                                                         \
      for (int kk = 0; kk < 2; ++kk)                                            \
        af[m][kk] = *(const bf16x8*)(Ab + arow * 128 + (((kk * 4 + fg) ^ (fr & 7)) * 16)); \
    }                                                                           \
    _Pragma("unroll")                                                           \
    for (int n = 0; n < 2; ++n) {                                               \
      const int brow = (NH) * 128 + n * 64 + wc * 16 + fr;                      \
      _Pragma("unroll")                                                         \
      for (int kk = 0; kk < 2; ++kk)                                            \
        bfv[n][kk] = *(const bf16x8*)(Bb + brow * 128 + (((kk * 4 + fg) ^ (fr & 7)) * 16)); \
    }                                                                           \
    if (DOSTAGE) stageHT(SBUF, SKT, SMAT, SHALF);                               \
    __builtin_amdgcn_sched_barrier(0);                                          \
    __builtin_amdgcn_s_barrier();                                               \
    __builtin_amdgcn_sched_barrier(0);                                          \
    __builtin_amdgcn_s_setprio(1);                                              \
    _Pragma("unroll")                                                           \
    for (int m = 0; m < 4; ++m)                                                 \
      _Pragma("unroll")                                                         \
      for (int n = 0; n < 2; ++n) {                                             \
        acc[(MH) * 4 + m][(NH) * 2 + n] = __builtin_amdgcn_mfma_f32_16x16x32_bf16( \
            af[m][0], bfv[n][0], acc[(MH) * 4 + m][(NH) * 2 + n], 0, 0, 0);     \
        acc[(MH) * 4 + m][(NH) * 2 + n] = __builtin_amdgcn_mfma_f32_16x16x32_bf16( \
            af[m][1], bfv[n][1], acc[(MH) * 4 + m][(NH) * 2 + n], 0, 0, 0);     \
      }                                                                         \
    __builtin_amdgcn_s_setprio(0);                                              \
    __builtin_amdgcn_sched_barrier(0);                                          \
  }

__global__ __launch_bounds__(512) void gemm256p_swiglu(
    const unsigned short* __restrict__ A, const unsigned short* __restrict__ B,
    unsigned short* __restrict__ C, int M, int N, int K, int ldc) {
  __shared__ unsigned short Al[2][256 * 64];
  __shared__ unsigned short Bl[2][256 * 64];
  const int tid = threadIdx.x;
  const int wid = tid >> 6, lane = tid & 63;
  const int wr = wid >> 2, wc = wid & 3;     // 2M x 4N waves
  const int fr = lane & 15, fg = lane >> 4;
  const int nwg = gridDim.x * gridDim.y;     // 352, %8==0
  int flat = blockIdx.y * gridDim.x + blockIdx.x;
  flat = (flat & 7) * (nwg >> 3) + (flat >> 3);
  const int bx = flat / gridDim.y;
  const int by = flat % gridDim.y;
  const long rowBase = (long)by * 256;
  const long colBase = (long)bx * 256;
  const int srow_l = tid >> 3;               // 0..63 within a stage inst
  const int sch = tid & 7;

  const f32x4 z4 = {0.f, 0.f, 0.f, 0.f};
  f32x4 acc[8][4];
#pragma unroll
  for (int m = 0; m < 8; ++m)
#pragma unroll
    for (int n = 0; n < 4; ++n) acc[m][n] = z4;

  // stage one half-tile (128 rows x 64 cols) = 2 global_load_lds / thread
  auto stageHT = [&](int buf, int kt, int mat, int half) {
    const unsigned short* G = mat ? B : A;
    const long base = mat ? colBase : rowBase;
    char* L = (char*)(mat ? Bl[buf] : Al[buf]) + half * 16384;
    const long kOff = (long)kt * 64;
#pragma unroll
    for (int i = 0; i < 2; ++i) {
      const int row = half * 128 + i * 64 + srow_l;
      async_cp16(G + (base + row) * K + kOff + ((sch ^ (row & 7)) * 8),
                 L + i * 8192 + wid * 1024);
    }
  };

  const int nkt = K >> 6;                    // 16
  // prologue: step0 all 4 half-tiles + step1 A0,B0 (6 HT = 12 insts)
  stageHT(0, 0, 0, 0); stageHT(0, 0, 1, 0);
  stageHT(0, 0, 0, 1); stageHT(0, 0, 1, 1);
  stageHT(1, 1, 0, 0); stageHT(1, 1, 1, 0);
  asm volatile("s_waitcnt vmcnt(4)" ::: "memory");   // step0 landed
  __builtin_amdgcn_sched_barrier(0);
  __builtin_amdgcn_s_barrier();
  __builtin_amdgcn_sched_barrier(0);

  for (int kt = 0; kt < nkt; ++kt) {
    const int buf = kt & 1, nbuf = buf ^ 1;
    const bool s1 = (kt + 1 < nkt), s2 = (kt + 2 < nkt);
    PH256(buf, 0, 0, s1, nbuf, kt + 1, 0, 1);        // stage (t+1).A1
    __builtin_amdgcn_s_barrier();
    __builtin_amdgcn_sched_barrier(0);
    PH256(buf, 0, 1, s1, nbuf, kt + 1, 1, 1);        // stage (t+1).B1
    __builtin_amdgcn_s_barrier();
    __builtin_amdgcn_sched_barrier(0);
    PH256(buf, 1, 0, s2, buf, kt + 2, 0, 0);         // stage (t+2).A0 (A0 dead)
    __builtin_amdgcn_s_barrier();
    __builtin_amdgcn_sched_barrier(0);
    PH256(buf, 1, 1, s2, buf, kt + 2, 1, 0);         // stage (t+2).B0 (B0 dead)
    if (s2) asm volatile("s_waitcnt vmcnt(4)" ::: "memory");   // t+1 landed
    else    asm volatile("s_waitcnt vmcnt(0)" ::: "memory");   // tail drain
    __builtin_amdgcn_sched_barrier(0);
    __builtin_amdgcn_s_barrier();                    // boundary
    __builtin_amdgcn_sched_barrier(0);
  }

  // fused SwiGLU epilogue (col parity = fr parity; pair via lane^1)
  const int erow = fg * 4;
  const int even = !(fr & 1);
#pragma unroll
  for (int mh = 0; mh < 2; ++mh)
#pragma unroll
    for (int m = 0; m < 4; ++m) {
      const long r0 = rowBase + mh * 128 + m * 32 + wr * 16 + erow;
#pragma unroll
      for (int nh = 0; nh < 2; ++nh)
#pragma unroll
        for (int n = 0; n < 2; ++n) {
          const long col = colBase + nh * 128 + n * 64 + wc * 16 + fr;
          const long fcol = col >> 1;
#pragma unroll
          for (int r = 0; r < 4; ++r) {
            const float own = acc[mh * 4 + m][nh * 2 + n][r];
            const float oth = __shfl_xor(own, 1);
            if (even) {
              const float s = own * oth / (1.f + __expf(-own));
              C[(r0 + r) * ldc + fcol] = f2bf(s);
            }
          }
        }
    }
}

// ---------- flash attention, causal, 16 heads x d_k=64 (FROZEN best form) ----------
#define KSTR 72
__global__ __launch_bounds__(256) void attn_kernel(
    const unsigned short* __restrict__ QK, const unsigned short* __restrict__ Vt,
    unsigned short* __restrict__ O) {
  __shared__ unsigned short Ks[2][64 * KSTR];
  const int bh = blockIdx.x;
  const int b = bh >> 4, h = bh & 15;
  const int tid = threadIdx.x;
  const int wid = tid >> 6, lane = tid & 63;
  const int fr = lane & 15, g = lane >> 4;
  const long rowb = (long)b * TSEQ;
  const int hoff = h * 64;
  const float C2 = 0.18033688011112042f;         // 0.125 * log2(e)

  const int ki = tid >> 3;                       // 0..31
  const int kcol = (tid & 7) * 8;
  const int kgrow = 8 * ((ki & 15) >> 2) + (ki & 3) + ((ki >> 4) << 2);

  const unsigned short* Kg = QK + rowb * 2048 + 1024 + hoff;
  const unsigned short* Vrow = Vt + (long)(hoff + fr) * 4096 + rowb + g * 8;
  const f32x4 z4 = {0.f, 0.f, 0.f, 0.f};
  bf16x8 onesv;
#pragma unroll
  for (int j = 0; j < 8; ++j) onesv[j] = (__bf16)1.0f;

#pragma unroll
  for (int phase = 0; phase < 2; ++phase) {
    const int qblk = phase ? (31 - blockIdx.y) : blockIdx.y;
    const int qbase = qblk * 64 + wid * 16;
    const int qg = qbase + fr;
    const int nkt = qblk + 1;

    const unsigned short* qrow = QK + (rowb + qbase + fr) * 2048 + hoff + g * 8;
    const bf16x8 qb0 = *reinterpret_cast<const bf16x8*>(qrow);
    const bf16x8 qb1 = *reinterpret_cast<const bf16x8*>(qrow + 32);

    f32x4 acc[4];
#pragma unroll
    for (int d = 0; d < 4; ++d) acc[d] = z4;
    f32x4 accL = z4;
    float mrun = -1e30f;

    uint4 kr0 = *reinterpret_cast<const uint4*>(Kg + (long)kgrow * 2048 + kcol);
    uint4 kr1 = *reinterpret_cast<const uint4*>(Kg + (long)(32 + kgrow) * 2048 + kcol);

    __syncthreads();

    for (int kt = 0; kt < nkt; ++kt) {
      unsigned short* Kb = Ks[kt & 1];
      *reinterpret_cast<uint4*>(&Kb[ki * KSTR + kcol]) = kr0;
      *reinterpret_cast<uint4*>(&Kb[(32 + ki) * KSTR + kcol]) = kr1;
      __syncthreads();
      const int kbase = kt * 64;
      if (kt + 1 < nkt) {
        kr0 = *reinterpret_cast<const uint4*>(Kg + (long)(kbase + 64 + kgrow) * 2048 + kcol);
        kr1 = *reinterpret_cast<const uint4*>(Kg + (long)(kbase + 96 + kgrow) * 2048 + kcol);
      }
      bf16x8 vf[4][2];
#pragma unroll
      for (int db = 0; db < 4; ++db)
#pragma unroll
        for (int ks = 0; ks < 2; ++ks)
          vf[db][ks] = *reinterpret_cast<const bf16x8*>(Vrow + (size_t)db * 16 * 4096 + kbase + ks * 32);

      f32x4 s1[2], s2[2];
#pragma unroll
      for (int ks = 0; ks < 2; ++ks) {
        const unsigned short* ra = &Kb[(ks * 32 + fr) * KSTR];
        const unsigned short* rc = &Kb[(ks * 32 + 16 + fr) * KSTR];
        f32x4 t1 = z4, t2 = z4;
        t1 = __builtin_amdgcn_mfma_f32_16x16x32_bf16(*reinterpret_cast<const bf16x8*>(ra + g * 8), qb0, t1, 0, 0, 0);
        t1 = __builtin_amdgcn_mfma_f32_16x16x32_bf16(*reinterpret_cast<const bf16x8*>(ra + 32 + g * 8), qb1, t1, 0, 0, 0);
        t2 = __builtin_amdgcn_mfma_f32_16x16x32_bf16(*reinterpret_cast<const bf16x8*>(rc + g * 8), qb0, t2, 0, 0, 0);
        t2 = __builtin_amdgcn_mfma_f32_16x16x32_bf16(*reinterpret_cast<const bf16x8*>(rc + 32 + g * 8), qb1, t2, 0, 0, 0);
        s1[ks] = t1; s2[ks] = t2;
      }

      float sc[16];
      if (kt + 1 < nkt) {
#pragma unroll
        for (int ks = 0; ks < 2; ++ks)
#pragma unroll
          for (int j = 0; j < 4; ++j) {
            sc[ks * 8 + j] = s1[ks][j];
            sc[ks * 8 + 4 + j] = s2[ks][j];
          }
      } else {
        const int kb8 = kbase + 8 * g;
#pragma unroll
        for (int ks = 0; ks < 2; ++ks)
#pragma unroll
          for (int j = 0; j < 4; ++j) {
            sc[ks * 8 + j]     = (kb8 + ks * 32 + j     <= qg) ? s1[ks][j] : -1e30f;
            sc[ks * 8 + 4 + j] = (kb8 + ks * 32 + 4 + j <= qg) ? s2[ks][j] : -1e30f;
          }
      }
      const float t0 = fmaxf(fmaxf(sc[0], sc[1]), sc[2]);
      const float t1 = fmaxf(fmaxf(sc[3], sc[4]), sc[5]);
      const float t2 = fmaxf(fmaxf(sc[6], sc[7]), sc[8]);
      const float t3 = fmaxf(fmaxf(sc[9], sc[10]), sc[11]);
      const float t4 = fmaxf(fmaxf(sc[12], sc[13]), sc[14]);
      float tmax = fmaxf(fmaxf(fmaxf(t0, t1), t2), fmaxf(fmaxf(t3, t4), sc[15]));
      const float p1 = __shfl_xor(tmax, 16);
      const float p2 = __shfl_xor(tmax, 32);
      const float p3 = __shfl_xor(tmax, 48);
      tmax = fmaxf(fmaxf(tmax, p1), fmaxf(p2, p3));
      if (__any(tmax > mrun)) {
        const float mnew = fmaxf(mrun, tmax);
        const float alpha = exp2f((mrun - mnew) * C2);
#pragma unroll
        for (int db = 0; db < 4; ++db)
#pragma unroll
          for (int r = 0; r < 4; ++r) acc[db][r] *= alpha;
#pragma unroll
        for (int r = 0; r < 4; ++r) accL[r] *= alpha;
        mrun = mnew;
      }
      const float m2 = mrun * C2;
      bf16x8 pbv[2];
#pragma unroll
      for (int ks = 0; ks < 2; ++ks)
#pragma unroll
        for (int j = 0; j < 8; ++j)
          pbv[ks][j] = (__bf16)exp2f(fmaf(sc[ks * 8 + j], C2, -m2));

#pragma unroll
      for (int db = 0; db < 4; ++db) {
        acc[db] = __builtin_amdgcn_mfma_f32_16x16x32_bf16(vf[db][0], pbv[0], acc[db], 0, 0, 0);
        acc[db] = __builtin_amdgcn_mfma_f32_16x16x32_bf16(vf[db][1], pbv[1], acc[db], 0, 0, 0);
      }
      accL = __builtin_amdgcn_mfma_f32_16x16x32_bf16(onesv, pbv[0], accL, 0, 0, 0);
      accL = __builtin_amdgcn_mfma_f32_16x16x32_bf16(onesv, pbv[1], accL, 0, 0, 0);
    }

    const float inv = 1.f / accL[0];
    unsigned short* orow = O + (rowb + qbase + fr) * DM + hoff;
#pragma unroll
    for (int db = 0; db < 4; ++db) {
      uint2 pk;
      pk.x = (unsigned int)f2bf(acc[db][0] * inv) | ((unsigned int)f2bf(acc[db][1] * inv) << 16);
      pk.y = (unsigned int)f2bf(acc[db][2] * inv) | ((unsigned int)f2bf(acc[db][3] * inv) << 16);
      *reinterpret_cast<uint2*>(orow + db * 16 + g * 4) = pk;
    }
  }
}

// ---------- workspace layout (lifetime-reused) ----------
static constexpr size_t OFF_WQKV = 0;          // [3072,1024] bf16
static constexpr size_t OFF_WO   = 6291456;    // [1024,1024] bf16
static constexpr size_t OFF_W13  = 8388608;    // [5632,1024] bf16 interleaved
static constexpr size_t OFF_W2   = 19922944;   // [1024,2816] bf16
static constexpr size_t OFF_H    = 25690112;   // [4096,1024] bf16
static constexpr size_t OFF_X2   = 34078720;   // [4096,1024] bf16 residual stream, 8MB
static constexpr size_t OFF_CS   = 50855936;   // [4096,32] float2, 1MB
static constexpr size_t OFF_QK   = 51904512;   // [4096,2048] bf16 (later: S [4096,2816])
static constexpr size_t OFF_VT   = 68681728;   // [1024,(h,d)][4096 (b,t)] bf16, 8MB
static constexpr size_t OFF_HO   = 77070336;   // [4096,1024] bf16

extern "C" void kernel_launch(void* const* d_in, const int* in_sizes, int n_in,
                              void* d_out, int out_size, void* d_ws, size_t ws_size,
                              hipStream_t stream) {
  const float* x  = (const float*)d_in[0];
  const int* tpos = (const int*)d_in[1];
  const float* WQ = (const float*)d_in[2];
  const float* WK = (const float*)d_in[3];
  const float* WV = (const float*)d_in[4];
  const float* WO = (const float*)d_in[5];
  const float* W1 = (const float*)d_in[6];
  const float* W2 = (const float*)d_in[7];
  const float* W3 = (const float*)d_in[8];
  const float* g1 = (const float*)d_in[9];
  const float* g2 = (const float*)d_in[10];
  float* out = (float*)d_out;

  char* ws = (char*)d_ws;
  unsigned short* Wqkv = (unsigned short*)(ws + OFF_WQKV);
  unsigned short* Wo   = (unsigned short*)(ws + OFF_WO);
  unsigned short* W13i = (unsigned short*)(ws + OFF_W13);
  unsigned short* W2p  = (unsigned short*)(ws + OFF_W2);
  unsigned short* hbuf = (unsigned short*)(ws + OFF_H);
  unsigned short* x2b  = (unsigned short*)(ws + OFF_X2);
  float2* cs           = (float2*)(ws + OFF_CS);
  unsigned short* QKb  = (unsigned short*)(ws + OFF_QK);
  unsigned short* Sbuf = (unsigned short*)(ws + OFF_QK);   // reuse after attn
  unsigned short* Vtb  = (unsigned short*)(ws + OFF_VT);
  unsigned short* Ho   = (unsigned short*)(ws + OFF_HO);

  // weight converts + cs table + rmsnorm1, one launch
  prep_kernel<<<PREP_BLOCKS + BT_ROWS, 256, 0, stream>>>(
      WQ, WK, WV, WO, W1, W3, W2, tpos, Wqkv, Wo, W13i, W2p, cs, x, g1, hbuf);

  // attention sublayer
  gemm_bt<4, 128, 1><<<dim3(16, 32), 256, 0, stream>>>(hbuf, Wqkv, QKb, nullptr, cs, BT_ROWS, 2048, 1024, 2048);
  gemm_bt<0, 64, 1><<<dim3(64, 8), 256, 0, stream>>>(Wqkv + 2048 * 1024, hbuf, Vtb, nullptr, nullptr, 1024, BT_ROWS, 1024, BT_ROWS);
  attn_kernel<<<dim3(32, 16), 256, 0, stream>>>(QKb, Vtb, Ho);
  gemm_bt<5, 64, 1><<<dim3(16, 32), 256, 0, stream>>>(Ho, Wo, x2b, x, nullptr, BT_ROWS, 1024, 1024, 1024);

  // FFN sublayer: W13 via 256^2 8-phase counted-vmcnt GEMM + fused SwiGLU
  rmsnorm_bf16_kernel<<<BT_ROWS, 256, 0, stream>>>(x2b, g2, hbuf);
  gemm256p_swiglu<<<dim3(22, 16), 512, 0, stream>>>(hbuf, W13i, Sbuf, BT_ROWS, 2 * DFFP, 1024, DFFP);
  gemm_bt<6, 64, 1><<<dim3(16, 32), 256, 0, stream>>>(Sbuf, W2p, out, (const float*)(const void*)x2b, nullptr, BT_ROWS, 1024, DFFP, 1024);
}

// Round 28
// 241.519 us; speedup vs baseline: 1.1203x; 1.1203x over previous
//
#include <hip/hip_runtime.h>
#include <cstdint>

// ---------- sizes ----------
#define BT_ROWS 4096      // B*T
#define DM      1024
#define DFF     2730
#define DFFP    2816      // padded to /128
#define TSEQ    2048

typedef float  f32x4  __attribute__((ext_vector_type(4)));
typedef __bf16 bf16x8 __attribute__((ext_vector_type(8)));

typedef __attribute__((address_space(1))) const unsigned int as1_uint;
typedef __attribute__((address_space(3))) unsigned int       as3_uint;

__device__ __forceinline__ unsigned short f2bf(float f) {
  union { float f; unsigned int u; } v; v.f = f;
  unsigned int u = v.u;
  return (unsigned short)((u + 0x7fffu + ((u >> 16) & 1u)) >> 16);  // RNE
}
__device__ __forceinline__ float bf2f(unsigned int b) {
  union { unsigned int u; float f; } v; v.u = b << 16;
  return v.f;
}

__device__ __forceinline__ void async_cp16(const void* g, void* l) {
  // 16B-wide global->LDS DMA; LDS dest is wave-uniform base + lane*16
  __builtin_amdgcn_global_load_lds((as1_uint*)(uintptr_t)g, (as3_uint*)(uintptr_t)l, 16, 0, 0);
}

// ---------- fused prep (vectorized) + rmsnorm1 (appended blocks) ----------
#define PREP_BLOCKS 12672
__global__ void prep_kernel(const float* __restrict__ WQ, const float* __restrict__ WK,
                            const float* __restrict__ WV, const float* __restrict__ WOp,
                            const float* __restrict__ W1, const float* __restrict__ W3,
                            const float* __restrict__ W2, const int* __restrict__ pos,
                            unsigned short* __restrict__ Wqkv, unsigned short* __restrict__ Wo,
                            unsigned short* __restrict__ W13i, unsigned short* __restrict__ W2p,
                            float2* __restrict__ cs,
                            const float* __restrict__ x, const float* __restrict__ g1,
                            unsigned short* __restrict__ hbuf) {
  if (blockIdx.x >= PREP_BLOCKS) {           // rmsnorm1: one block per row
    const int row = blockIdx.x - PREP_BLOCKS, tid = threadIdx.x;
    const float4 xv = reinterpret_cast<const float4*>(x + (long)row * DM)[tid];
    float ss = xv.x * xv.x + xv.y * xv.y + xv.z * xv.z + xv.w * xv.w;
#pragma unroll
    for (int o = 32; o > 0; o >>= 1) ss += __shfl_xor(ss, o);
    __shared__ float wsum[4];
    if ((tid & 63) == 0) wsum[tid >> 6] = ss;
    __syncthreads();
    const float inv = rsqrtf((wsum[0] + wsum[1] + wsum[2] + wsum[3]) * (1.f / DM) + 1e-5f);
    const float4 gv = reinterpret_cast<const float4*>(g1)[tid];
    ushort4 o4;
    o4.x = f2bf(xv.x * inv * gv.x);
    o4.y = f2bf(xv.y * inv * gv.y);
    o4.z = f2bf(xv.z * inv * gv.z);
    o4.w = f2bf(xv.w * inv * gv.w);
    reinterpret_cast<ushort4*>(hbuf + (long)row * DM)[tid] = o4;
    return;
  }
  long grp = (long)blockIdx.x * 256 + threadIdx.x;
  if (grp < 1048576) {                       // 4 square 1024x1024 mats, float4
    const int j = (int)(grp >> 18);
    const long t = (grp & 262143L) * 4;
    const float* s = (j == 0) ? WQ : (j == 1) ? WK : (j == 2) ? WV : WOp;
    unsigned short* d = (j < 3) ? (Wqkv + (size_t)j * 1048576) : Wo;
    const float4 v = *reinterpret_cast<const float4*>(s + t);
    *reinterpret_cast<ushort4*>(d + t) =
        make_ushort4(f2bf(v.x), f2bf(v.y), f2bf(v.z), f2bf(v.w));
    return;
  }
  grp -= 1048576;
  if (grp < 1441792) {                       // W1/W3 row-interleaved + pad
    const int half = (int)(grp / 720896);
    const long t = (grp % 720896) * 4;
    const int r = (int)(t >> 10), c = (int)(t & 1023);
    ushort4 o = make_ushort4(0, 0, 0, 0);
    if (r < DFF) {
      const float4 v = *reinterpret_cast<const float4*>(((half ? W3 : W1) + (long)r * 1024 + c));
      o = make_ushort4(f2bf(v.x), f2bf(v.y), f2bf(v.z), f2bf(v.w));
    }
    *reinterpret_cast<ushort4*>(W13i + ((long)2 * r + half) * 1024 + c) = o;
    return;
  }
  grp -= 1441792;
  if (grp < 720896) {                        // W2 col-padded (rows of 2816, /4)
    const long t = grp * 4;
    const int r = (int)(t / DFFP), c = (int)(t % DFFP);
    const float* src = W2 + (long)r * DFF + c;
    ushort4 o;
    o.x = (c     < DFF) ? f2bf(src[0]) : 0;
    o.y = (c + 1 < DFF) ? f2bf(src[1]) : 0;
    o.z = (c + 2 < DFF) ? f2bf(src[2]) : 0;
    o.w = (c + 3 < DFF) ? f2bf(src[3]) : 0;
    *reinterpret_cast<ushort4*>(W2p + t) = o;
    return;
  }
  grp -= 720896;
  if (grp < 32768) {                         // RoPE cos/sin table, 4 entries
    const long i0 = grp * 4;
    const int r = (int)(i0 >> 5);
    const float p = (float)pos[r];
#pragma unroll
    for (int j = 0; j < 4; ++j) {
      const int i = (int)((i0 + j) & 31);
      const float f = powf(10000.f, -(float)(2 * i) * (1.f / 64.f));
      float sv, cv;
      sincosf(p * f, &sv, &cv);
      cs[i0 + j] = make_float2(cv, sv);
    }
  }
}

// ---------- RMSNorm (bf16 in -> bf16 out), one block per row ----------
__global__ void rmsnorm_bf16_kernel(const unsigned short* __restrict__ x, const float* __restrict__ g,
                                    unsigned short* __restrict__ out) {
  const int row = blockIdx.x, tid = threadIdx.x;
  const ushort4 xu = reinterpret_cast<const ushort4*>(x + (long)row * DM)[tid];
  const float x0 = bf2f(xu.x), x1 = bf2f(xu.y), x2 = bf2f(xu.z), x3 = bf2f(xu.w);
  float ss = x0 * x0 + x1 * x1 + x2 * x2 + x3 * x3;
#pragma unroll
  for (int o = 32; o > 0; o >>= 1) ss += __shfl_xor(ss, o);
  __shared__ float wsum[4];
  if ((tid & 63) == 0) wsum[tid >> 6] = ss;
  __syncthreads();
  const float inv = rsqrtf((wsum[0] + wsum[1] + wsum[2] + wsum[3]) * (1.f / DM) + 1e-5f);
  const float4 gv = reinterpret_cast<const float4*>(g)[tid];
  ushort4 o4;
  o4.x = f2bf(x0 * inv * gv.x);
  o4.y = f2bf(x1 * inv * gv.y);
  o4.z = f2bf(x2 * inv * gv.z);
  o4.w = f2bf(x3 * inv * gv.w);
  reinterpret_cast<ushort4*>(out + (long)row * DM)[tid] = o4;
}

// ---------- GEMM: C[M,N] = A[M,K] * B[N,K]^T  (bf16 in, fp32 acc) ----------
// 128xBN tile, BK=64, XOR-swizzled LDS (pre-swizzled global src).
// DB=1: 2-phase double-buffer via __syncthreads (1 barrier/K-step, 2x LDS);
// DB=0: single-buffer (2 barriers/K-step, half LDS).
// Rule (R18-R27 measured): DB=0 iff grid/CU exceeds the DB=1 LDS limit
// (only W13: 1408 blocks). Coarse counted-vmcnt (R24), 256-tile 2-barrier
// (R22), and a blind 8-phase port (R26) all regress: the verified 8-phase
// template's exact barrier choreography is required and was not reproducible.
// T1 XCD swizzle, y-fastest decode (B-panels L2-resident per XCD).
// EPI 0: bf16 store; EPI 3: fused SwiGLU; EPI 4: fused RoPE store;
// EPI 5: bf16 store of acc + f32 resid; EPI 6: f32 store of acc + bf16 resid
template <int EPI, int BN, int DB>
__global__ __launch_bounds__(256) void gemm_bt(
    const unsigned short* __restrict__ A, const unsigned short* __restrict__ B,
    void* __restrict__ C, const float* __restrict__ resid,
    const float2* __restrict__ CS,
    int M, int N, int K, int ldc) {
  constexpr int WNF = BN / 32;              // B-frags per wave (4 or 2)
  __shared__ unsigned short As[(DB + 1) * 128 * 64];
  __shared__ unsigned short Bs[(DB + 1) * BN * 64];
  const int tid = threadIdx.x;
  const int wid = tid >> 6;
  const int lane = tid & 63;
  // T1 XCD swizzle (y-fastest): XCD k gets logical flats k*(nwg/8)..,
  // decoded bx = flat / gridDim.y (contiguous columns), by = flat % gridDim.y
  const int nwg = gridDim.x * gridDim.y;
  int flat = blockIdx.y * gridDim.x + blockIdx.x;
  flat = (flat & 7) * (nwg >> 3) + (flat >> 3);
  const int bx = flat / gridDim.y;
  const int by = flat % gridDim.y;
  const long rowBase = (long)by * 128;
  const long colBase = (long)bx * BN;
  const int wm = (wid >> 1) * 64;
  const int wn = (wid & 1) * (BN / 2);
  const int srow = wid * 8 + (lane >> 3);   // staging row within 32-row group
  const int sc   = lane & 7;                // staging 16B chunk
  const int cs   = (sc ^ (srow & 7)) * 8;   // pre-swizzled source chunk (elems)
  const int fr = lane & 15;                 // fragment row
  const int fg = lane >> 4;                 // fragment k-group

  const f32x4 z4 = {0.f, 0.f, 0.f, 0.f};
  f32x4 acc[4][WNF];
#pragma unroll
  for (int m = 0; m < 4; ++m)
#pragma unroll
    for (int n = 0; n < WNF; ++n) acc[m][n] = z4;

  auto stage = [&](int buf, int kt) {
    const long kOff = (long)kt * 64 + cs;
    char* AsB = (char*)As + buf * 16384;
    char* BsB = (char*)Bs + buf * (BN * 128);
#pragma unroll
    for (int i = 0; i < 4; ++i)
      async_cp16(A + (rowBase + i * 32 + srow) * K + kOff, AsB + i * 4096 + wid * 1024);
#pragma unroll
    for (int i = 0; i < WNF; ++i)
      async_cp16(B + (colBase + i * 32 + srow) * K + kOff, BsB + i * 4096 + wid * 1024);
  };

  auto compute = [&](int buf) {
    const char* AsB = (const char*)As + buf * 16384;
    const char* BsB = (const char*)Bs + buf * (BN * 128);
#pragma unroll
    for (int kk = 0; kk < 2; ++kk) {
      bf16x8 af[4], bfr[WNF];
#pragma unroll
      for (int m = 0; m < 4; ++m)
        af[m] = *(const bf16x8*)(AsB + (wm + m * 16 + fr) * 128 + (((kk * 4 + fg) ^ (fr & 7)) * 16));
#pragma unroll
      for (int n = 0; n < WNF; ++n)
        bfr[n] = *(const bf16x8*)(BsB + (wn + n * 16 + fr) * 128 + (((kk * 4 + fg) ^ (fr & 7)) * 16));
#pragma unroll
      for (int m = 0; m < 4; ++m)
#pragma unroll
        for (int n = 0; n < WNF; ++n)
          acc[m][n] = __builtin_amdgcn_mfma_f32_16x16x32_bf16(af[m], bfr[n], acc[m][n], 0, 0, 0);
    }
  };

  const int nkt = K >> 6;
  if (DB) {
    stage(0, 0);
    __syncthreads();                        // drain vmcnt(0): buf0 ready
    for (int kt = 0; kt < nkt; ++kt) {
      if (kt + 1 < nkt) stage((kt + 1) & 1, kt + 1);   // issue-early (in flight)
      compute(kt & 1);
      __syncthreads();                      // drain-late: next buf ready
    }
  } else {
    for (int kt = 0; kt < nkt; ++kt) {
      if (kt) __syncthreads();              // prev compute done before overwrite
      stage(0, kt);
      __syncthreads();                      // vmcnt(0) drained -> LDS ready
      compute(0);
    }
  }

  const int erow = fg * 4;  // C: col = lane&15, row = (lane>>4)*4 + reg
  if (EPI == 0) {
    unsigned short* Cp = (unsigned short*)C;
#pragma unroll
    for (int m = 0; m < 4; ++m) {
      const long r0 = rowBase + wm + m * 16 + erow;
#pragma unroll
      for (int n = 0; n < WNF; ++n) {
        const long col = colBase + wn + n * 16 + fr;
#pragma unroll
        for (int r = 0; r < 4; ++r) Cp[(r0 + r) * ldc + col] = f2bf(acc[m][n][r]);
      }
    }
  } else if (EPI == 5) {
    // bf16 store of acc + f32 residual (residual stream -> bf16)
    unsigned short* Cp = (unsigned short*)C;
#pragma unroll
    for (int m = 0; m < 4; ++m) {
      const long r0 = rowBase + wm + m * 16 + erow;
#pragma unroll
      for (int n = 0; n < WNF; ++n) {
        const long col = colBase + wn + n * 16 + fr;
#pragma unroll
        for (int r = 0; r < 4; ++r) {
          const long o = (r0 + r) * ldc + col;
          Cp[o] = f2bf(acc[m][n][r] + resid[o]);
        }
      }
    }
  } else if (EPI == 6) {
    // f32 store of acc + bf16 residual
    float* Cf = (float*)C;
    const unsigned short* Rb = (const unsigned short*)(const void*)resid;
#pragma unroll
    for (int m = 0; m < 4; ++m) {
      const long r0 = rowBase + wm + m * 16 + erow;
#pragma unroll
      for (int n = 0; n < WNF; ++n) {
        const long col = colBase + wn + n * 16 + fr;
#pragma unroll
        for (int r = 0; r < 4; ++r) {
          const long o = (r0 + r) * ldc + col;
          Cf[o] = acc[m][n][r] + bf2f(Rb[o]);
        }
      }
    }
  } else if (EPI == 3) {
    // fused SwiGLU: even col = u (W1 row), odd col = g (W3 row); out col/2
    unsigned short* Cp = (unsigned short*)C;
    const int even = !(fr & 1);
#pragma unroll
    for (int m = 0; m < 4; ++m) {
      const long r0 = rowBase + wm + m * 16 + erow;
#pragma unroll
      for (int n = 0; n < WNF; ++n) {
        const long col = colBase + wn + n * 16 + fr;
        const long fcol = col >> 1;
#pragma unroll
        for (int r = 0; r < 4; ++r) {
          const float own = acc[m][n][r];
          const float oth = __shfl_xor(own, 1);
          if (even) {
            const float s = own * oth / (1.f + __expf(-own));
            Cp[(r0 + r) * ldc + fcol] = f2bf(s);
          }
        }
      }
    }
  } else {
    // fused RoPE: pair (2i,2i+1) cols via lane^1; even: c*x0-s*x1, odd: s*x0+c*x1
    unsigned short* Cp = (unsigned short*)C;
    const int even = !(fr & 1);
#pragma unroll
    for (int m = 0; m < 4; ++m) {
      const long r0 = rowBase + wm + m * 16 + erow;
#pragma unroll
      for (int n = 0; n < WNF; ++n) {
        const long col = colBase + wn + n * 16 + fr;
        const int i = (int)((col & 63) >> 1);
#pragma unroll
        for (int r = 0; r < 4; ++r) {
          const float own = acc[m][n][r];
          const float oth = __shfl_xor(own, 1);
          const float2 cv = CS[(r0 + r) * 32 + i];
          const float v = even ? (cv.x * own - cv.y * oth) : (cv.y * oth + cv.x * own);
          Cp[(r0 + r) * ldc + col] = f2bf(v);
        }
      }
    }
  }
}

// ---------- flash attention, causal, 16 heads x d_k=64 (FROZEN best form) ----------
// S' = K*Q^T (swapped) with permuted K staging so P' lands in the PV B-frag
// layout. Block = 4 waves x 16 q-rows; qblk pair (y, 31-y) -> 33 tiles/block.
// lrun via ones-row MFMA (column-sum of P); parallel 3-hop max reduce.
#define KSTR 72
__global__ __launch_bounds__(256) void attn_kernel(
    const unsigned short* __restrict__ QK, const unsigned short* __restrict__ Vt,
    unsigned short* __restrict__ O) {
  __shared__ unsigned short Ks[2][64 * KSTR];
  const int bh = blockIdx.x;
  const int b = bh >> 4, h = bh & 15;
  const int tid = threadIdx.x;
  const int wid = tid >> 6, lane = tid & 63;
  const int fr = lane & 15, g = lane >> 4;
  const long rowb = (long)b * TSEQ;
  const int hoff = h * 64;
  const float C2 = 0.18033688011112042f;         // 0.125 * log2(e)

  // K staging map (per 32-row group, permuted rows)
  const int ki = tid >> 3;                       // 0..31
  const int kcol = (tid & 7) * 8;
  const int kgrow = 8 * ((ki & 15) >> 2) + (ki & 3) + ((ki >> 4) << 2);

  const unsigned short* Kg = QK + rowb * 2048 + 1024 + hoff;
  // V^T: Vt[(h*64+d)][b*2048 + t]
  const unsigned short* Vrow = Vt + (long)(hoff + fr) * 4096 + rowb + g * 8;
  const f32x4 z4 = {0.f, 0.f, 0.f, 0.f};
  bf16x8 onesv;
#pragma unroll
  for (int j = 0; j < 8; ++j) onesv[j] = (__bf16)1.0f;

#pragma unroll
  for (int phase = 0; phase < 2; ++phase) {
    const int qblk = phase ? (31 - blockIdx.y) : blockIdx.y;
    const int qbase = qblk * 64 + wid * 16;
    const int qg = qbase + fr;
    const int nkt = qblk + 1;

    const unsigned short* qrow = QK + (rowb + qbase + fr) * 2048 + hoff + g * 8;
    const bf16x8 qb0 = *reinterpret_cast<const bf16x8*>(qrow);
    const bf16x8 qb1 = *reinterpret_cast<const bf16x8*>(qrow + 32);

    f32x4 acc[4];
#pragma unroll
    for (int d = 0; d < 4; ++d) acc[d] = z4;
    f32x4 accL = z4;                             // ones-row MFMA: lrun per q-col
    float mrun = -1e30f;

    uint4 kr0 = *reinterpret_cast<const uint4*>(Kg + (long)kgrow * 2048 + kcol);
    uint4 kr1 = *reinterpret_cast<const uint4*>(Kg + (long)(32 + kgrow) * 2048 + kcol);

    __syncthreads();   // prev phase's LDS reads complete before re-staging

    for (int kt = 0; kt < nkt; ++kt) {
      unsigned short* Kb = Ks[kt & 1];
      *reinterpret_cast<uint4*>(&Kb[ki * KSTR + kcol]) = kr0;
      *reinterpret_cast<uint4*>(&Kb[(32 + ki) * KSTR + kcol]) = kr1;
      __syncthreads();   // writes visible; prev tile's compute (other buf) done
      const int kbase = kt * 64;
      if (kt + 1 < nkt) {
        kr0 = *reinterpret_cast<const uint4*>(Kg + (long)(kbase + 64 + kgrow) * 2048 + kcol);
        kr1 = *reinterpret_cast<const uint4*>(Kg + (long)(kbase + 96 + kgrow) * 2048 + kcol);
      }
      // V fragments straight from global
      bf16x8 vf[4][2];
#pragma unroll
      for (int db = 0; db < 4; ++db)
#pragma unroll
        for (int ks = 0; ks < 2; ++ks)
          vf[db][ks] = *reinterpret_cast<const bf16x8*>(Vrow + (size_t)db * 16 * 4096 + kbase + ks * 32);

      // QK^T: per 32-k group: rows {fr, 16+fr}, contraction d=64 in 2 halves
      f32x4 s1[2], s2[2];
#pragma unroll
      for (int ks = 0; ks < 2; ++ks) {
        const unsigned short* ra = &Kb[(ks * 32 + fr) * KSTR];
        const unsigned short* rc = &Kb[(ks * 32 + 16 + fr) * KSTR];
        f32x4 t1 = z4, t2 = z4;
        t1 = __builtin_amdgcn_mfma_f32_16x16x32_bf16(*reinterpret_cast<const bf16x8*>(ra + g * 8), qb0, t1, 0, 0, 0);
        t1 = __builtin_amdgcn_mfma_f32_16x16x32_bf16(*reinterpret_cast<const bf16x8*>(ra + 32 + g * 8), qb1, t1, 0, 0, 0);
        t2 = __builtin_amdgcn_mfma_f32_16x16x32_bf16(*reinterpret_cast<const bf16x8*>(rc + g * 8), qb0, t2, 0, 0, 0);
        t2 = __builtin_amdgcn_mfma_f32_16x16x32_bf16(*reinterpret_cast<const bf16x8*>(rc + 32 + g * 8), qb1, t2, 0, 0, 0);
        s1[ks] = t1; s2[ks] = t2;
      }

      // lane's 16 raw scores: k = kbase + ks*32 + 8g + {j | 4+j}
      float sc[16];
      if (kt + 1 < nkt) {  // fully causal-visible tile: no mask
#pragma unroll
        for (int ks = 0; ks < 2; ++ks)
#pragma unroll
          for (int j = 0; j < 4; ++j) {
            sc[ks * 8 + j] = s1[ks][j];
            sc[ks * 8 + 4 + j] = s2[ks][j];
          }
      } else {
        const int kb8 = kbase + 8 * g;
#pragma unroll
        for (int ks = 0; ks < 2; ++ks)
#pragma unroll
          for (int j = 0; j < 4; ++j) {
            sc[ks * 8 + j]     = (kb8 + ks * 32 + j     <= qg) ? s1[ks][j] : -1e30f;
            sc[ks * 8 + 4 + j] = (kb8 + ks * 32 + 4 + j <= qg) ? s2[ks][j] : -1e30f;
          }
      }
      // max via max3 tree + 3 PARALLEL cross-lane hops (xor 16/32/48)
      const float t0 = fmaxf(fmaxf(sc[0], sc[1]), sc[2]);
      const float t1 = fmaxf(fmaxf(sc[3], sc[4]), sc[5]);
      const float t2 = fmaxf(fmaxf(sc[6], sc[7]), sc[8]);
      const float t3 = fmaxf(fmaxf(sc[9], sc[10]), sc[11]);
      const float t4 = fmaxf(fmaxf(sc[12], sc[13]), sc[14]);
      float tmax = fmaxf(fmaxf(fmaxf(t0, t1), t2), fmaxf(fmaxf(t3, t4), sc[15]));
      const float p1 = __shfl_xor(tmax, 16);
      const float p2 = __shfl_xor(tmax, 32);
      const float p3 = __shfl_xor(tmax, 48);
      tmax = fmaxf(fmaxf(tmax, p1), fmaxf(p2, p3));
      if (__any(tmax > mrun)) {                  // T13 exact: skip when alpha==1
        const float mnew = fmaxf(mrun, tmax);
        const float alpha = exp2f((mrun - mnew) * C2);
#pragma unroll
        for (int db = 0; db < 4; ++db)
#pragma unroll
          for (int r = 0; r < 4; ++r) acc[db][r] *= alpha;
#pragma unroll
        for (int r = 0; r < 4; ++r) accL[r] *= alpha;
        mrun = mnew;
      }
      const float m2 = mrun * C2;
      bf16x8 pbv[2];
#pragma unroll
      for (int ks = 0; ks < 2; ++ks)
#pragma unroll
        for (int j = 0; j < 8; ++j)
          pbv[ks][j] = (__bf16)exp2f(fmaf(sc[ks * 8 + j], C2, -m2));  // v_cvt_pk

      // PV: acc[db] += V^T-frag * P'-frag ; accL += ones * P' (= column sums)
#pragma unroll
      for (int db = 0; db < 4; ++db) {
        acc[db] = __builtin_amdgcn_mfma_f32_16x16x32_bf16(vf[db][0], pbv[0], acc[db], 0, 0, 0);
        acc[db] = __builtin_amdgcn_mfma_f32_16x16x32_bf16(vf[db][1], pbv[1], acc[db], 0, 0, 0);
      }
      accL = __builtin_amdgcn_mfma_f32_16x16x32_bf16(onesv, pbv[0], accL, 0, 0, 0);
      accL = __builtin_amdgcn_mfma_f32_16x16x32_bf16(onesv, pbv[1], accL, 0, 0, 0);
    }

    const float inv = 1.f / accL[0];             // every lane holds colsum(q=fr)
    unsigned short* orow = O + (rowb + qbase + fr) * DM + hoff;
#pragma unroll
    for (int db = 0; db < 4; ++db) {
      uint2 pk;
      pk.x = (unsigned int)f2bf(acc[db][0] * inv) | ((unsigned int)f2bf(acc[db][1] * inv) << 16);
      pk.y = (unsigned int)f2bf(acc[db][2] * inv) | ((unsigned int)f2bf(acc[db][3] * inv) << 16);
      *reinterpret_cast<uint2*>(orow + db * 16 + g * 4) = pk;
    }
  }
}

// ---------- workspace layout (lifetime-reused) ----------
static constexpr size_t OFF_WQKV = 0;          // [3072,1024] bf16
static constexpr size_t OFF_WO   = 6291456;    // [1024,1024] bf16
static constexpr size_t OFF_W13  = 8388608;    // [5632,1024] bf16 interleaved
static constexpr size_t OFF_W2   = 19922944;   // [1024,2816] bf16
static constexpr size_t OFF_H    = 25690112;   // [4096,1024] bf16
static constexpr size_t OFF_X2   = 34078720;   // [4096,1024] bf16 residual stream, 8MB
static constexpr size_t OFF_CS   = 50855936;   // [4096,32] float2, 1MB
static constexpr size_t OFF_QK   = 51904512;   // [4096,2048] bf16 (later: S [4096,2816])
static constexpr size_t OFF_VT   = 68681728;   // [1024,(h,d)][4096 (b,t)] bf16, 8MB
static constexpr size_t OFF_HO   = 77070336;   // [4096,1024] bf16

extern "C" void kernel_launch(void* const* d_in, const int* in_sizes, int n_in,
                              void* d_out, int out_size, void* d_ws, size_t ws_size,
                              hipStream_t stream) {
  const float* x  = (const float*)d_in[0];
  const int* tpos = (const int*)d_in[1];
  const float* WQ = (const float*)d_in[2];
  const float* WK = (const float*)d_in[3];
  const float* WV = (const float*)d_in[4];
  const float* WO = (const float*)d_in[5];
  const float* W1 = (const float*)d_in[6];
  const float* W2 = (const float*)d_in[7];
  const float* W3 = (const float*)d_in[8];
  const float* g1 = (const float*)d_in[9];
  const float* g2 = (const float*)d_in[10];
  float* out = (float*)d_out;

  char* ws = (char*)d_ws;
  unsigned short* Wqkv = (unsigned short*)(ws + OFF_WQKV);
  unsigned short* Wo   = (unsigned short*)(ws + OFF_WO);
  unsigned short* W13i = (unsigned short*)(ws + OFF_W13);
  unsigned short* W2p  = (unsigned short*)(ws + OFF_W2);
  unsigned short* hbuf = (unsigned short*)(ws + OFF_H);
  unsigned short* x2b  = (unsigned short*)(ws + OFF_X2);
  float2* cs           = (float2*)(ws + OFF_CS);
  unsigned short* QKb  = (unsigned short*)(ws + OFF_QK);
  unsigned short* Sbuf = (unsigned short*)(ws + OFF_QK);   // reuse after attn
  unsigned short* Vtb  = (unsigned short*)(ws + OFF_VT);
  unsigned short* Ho   = (unsigned short*)(ws + OFF_HO);

  // weight converts + cs table + rmsnorm1, one launch
  prep_kernel<<<PREP_BLOCKS + BT_ROWS, 256, 0, stream>>>(
      WQ, WK, WV, WO, W1, W3, W2, tpos, Wqkv, Wo, W13i, W2p, cs, x, g1, hbuf);

  // attention sublayer (QKV grid-starved at 512 blocks -> keep DB=1)
  gemm_bt<4, 128, 1><<<dim3(16, 32), 256, 0, stream>>>(hbuf, Wqkv, QKb, nullptr, cs, BT_ROWS, 2048, 1024, 2048);
  // Vt = Wv * h^T : coalesced V^T, BN=64
  gemm_bt<0, 64, 1><<<dim3(64, 8), 256, 0, stream>>>(Wqkv + 2048 * 1024, hbuf, Vtb, nullptr, nullptr, 1024, BT_ROWS, 1024, BT_ROWS);
  attn_kernel<<<dim3(32, 16), 256, 0, stream>>>(QKb, Vtb, Ho);
  // O-projection: residual stream stored as bf16
  gemm_bt<5, 64, 1><<<dim3(16, 32), 256, 0, stream>>>(Ho, Wo, x2b, x, nullptr, BT_ROWS, 1024, 1024, 1024);

  // FFN sublayer (W13: 1408 blocks, LDS-limited -> single-buffer DB=0)
  rmsnorm_bf16_kernel<<<BT_ROWS, 256, 0, stream>>>(x2b, g2, hbuf);
  gemm_bt<3, 128, 0><<<dim3(44, 32), 256, 0, stream>>>(hbuf, W13i, Sbuf, nullptr, nullptr, BT_ROWS, 2 * DFFP, 1024, DFFP);
  gemm_bt<6, 64, 1><<<dim3(16, 32), 256, 0, stream>>>(Sbuf, W2p, out, (const float*)(const void*)x2b, nullptr, BT_ROWS, 1024, DFFP, 1024);
}